// Round 3
// baseline (190.322 us; speedup 1.0000x reference)
//
#include <hip/hip_runtime.h>

#define IMG 1024

// entropy of a window sum s with n = 1/inv_n elements: -(p0*log2 p0 + p1*log2 p1)
__device__ __forceinline__ float ent(float s, float inv_n) {
    float p1 = s * inv_n;
    float p0 = 1.0f - p1;
    float l1 = (p1 > 0.0f) ? __log2f(p1) : 0.0f;
    float l0 = (p0 > 0.0f) ? __log2f(p0) : 0.0f;
    return -(p0 * l0 + p1 * l1);
}

__device__ __forceinline__ float bfly_sum(float v) {
#pragma unroll
    for (int m = 32; m >= 1; m >>= 1) v += __shfl_xor(v, m);
    return v;  // full 64-lane sum, broadcast
}

// Kernel 1: one 128x128 tile per block (2048 blocks), levels k=2..128.
// Wave w = 32x128 sub-tile (rows 32w..32w+31). Load i (i=0..15) is one fully
// contiguous 1 KiB wave segment covering rows {2i, 2i+1}:
//   hi = lane>>5 selects the row, lo = lane&31 selects cols 4lo..4lo+3.
// Level merges: vertical k=2 via shfl_xor(32); k=4 in-register; k=8/16/32 via
// shfl_xor(1/2/4); k=64/128 via 16 floats of LDS. Duplication per level:
// k2 x2 (hi), k4 x2, k8 x4, k16 x8, k32 x16 — folded into write-out scales.
__global__ __launch_bounds__(256, 4) void slice_k1(const float* __restrict__ x,
                                                   float* __restrict__ ws) {
    const int b    = blockIdx.x >> 6;    // image
    const int tile = blockIdx.x & 63;    // 8x8 tiles of 128x128
    const int tr = tile >> 3, tc = tile & 7;
    const int t = threadIdx.x;
    const int w = t >> 6, lane = t & 63;
    const int hi = lane >> 5, lo = lane & 31;

    const float* p = x + (size_t)b * (IMG * IMG)
                       + (size_t)(tr * 128 + w * 32 + hi) * IMG + (tc * 128 + lo * 4);

    float4 v[16];
#pragma unroll
    for (int i = 0; i < 16; ++i)
        v[i] = *(const float4*)(p + (size_t)(2 * i) * IMG);  // rows 2i+hi

    float e2 = 0.f, e4 = 0.f, e8 = 0.f, e16 = 0.f;
    float s4p[16];
#pragma unroll
    for (int i = 0; i < 16; ++i) {
        float h0 = v[i].x + v[i].y;          // cols 4lo..4lo+1, row 2i+hi
        float h1 = v[i].z + v[i].w;          // cols 4lo+2..4lo+3
        float s2a = h0 + __shfl_xor(h0, 32); // k=2 window (rows 2i, cols 4lo)
        float s2b = h1 + __shfl_xor(h1, 32); // k=2 window (rows 2i, cols 4lo+2)
        e2 += ent(s2a, 0.25f) + ent(s2b, 0.25f);
        s4p[i] = s2a + s2b;                  // 2 rows x 4 cols
    }
    float s4[8], s8[4], s16[2];
#pragma unroll
    for (int j = 0; j < 8; ++j) {            // k=4: rows 4j, cols 4lo
        s4[j] = s4p[2 * j] + s4p[2 * j + 1];
        e4 += ent(s4[j], 1.f / 16.f);
    }
#pragma unroll
    for (int m = 0; m < 4; ++m) {            // k=8: rows 8m, cols 8(lo>>1)
        float t8 = s4[2 * m] + s4[2 * m + 1];
        s8[m] = t8 + __shfl_xor(t8, 1);
        e8 += ent(s8[m], 1.f / 64.f);
    }
#pragma unroll
    for (int q = 0; q < 2; ++q) {            // k=16: rows 16q, cols 16(lo>>2)
        float t16 = s8[2 * q] + s8[2 * q + 1];
        s16[q] = t16 + __shfl_xor(t16, 2);
        e16 += ent(s16[q], 1.f / 256.f);
    }
    float t32 = s16[0] + s16[1];             // k=32: rows 32w, cols 32(lo>>3)
    float s32 = t32 + __shfl_xor(t32, 4);
    float e32 = ent(s32, 1.f / 1024.f);

    float E2  = bfly_sum(e2);
    float E4  = bfly_sum(e4);
    float E8  = bfly_sum(e8);
    float E16 = bfly_sum(e16);
    float E32 = bfly_sum(e32);

    __shared__ float wl[4][5];
    __shared__ float wl32[4][4];             // [wave][col-block of 32]
    if (lane == 0) {
        wl[w][0] = E2 * 0.5f;   wl[w][1] = E4 * 0.5f;  wl[w][2] = E8 * 0.25f;
        wl[w][3] = E16 * 0.125f; wl[w][4] = E32 * 0.0625f;
    }
    if (hi == 0 && (lo & 7) == 0) wl32[w][lo >> 3] = s32;
    __syncthreads();

    if (t < 8) {
        float r;
        if (t < 5) {
            r = wl[0][t] + wl[1][t] + wl[2][t] + wl[3][t];
        } else {
            float s64a = wl32[0][0] + wl32[0][1] + wl32[1][0] + wl32[1][1];
            float s64b = wl32[0][2] + wl32[0][3] + wl32[1][2] + wl32[1][3];
            float s64c = wl32[2][0] + wl32[2][1] + wl32[3][0] + wl32[3][1];
            float s64d = wl32[2][2] + wl32[2][3] + wl32[3][2] + wl32[3][3];
            if (t == 5) {
                r = ent(s64a, 1.f / 4096.f) + ent(s64b, 1.f / 4096.f)
                  + ent(s64c, 1.f / 4096.f) + ent(s64d, 1.f / 4096.f);
            } else {
                float s128 = s64a + s64b + s64c + s64d;
                r = (t == 6) ? ent(s128, 1.f / 16384.f) : s128;
            }
        }
        ws[(size_t)blockIdx.x * 8 + t] = r;  // {E2,E4,E8,E16,E32,E64sum,e128,s128}
    }
}

// Kernel 2: final per-image reduction + k=256. One wave per image; plain stores.
// Lane l = tile index within image (tr*8 + tc): x bit0 = l bit0, y bit0 = l bit3.
__global__ __launch_bounds__(64) void slice_k2(const float* __restrict__ ws,
                                               float* __restrict__ out) {
    const int b = blockIdx.x, l = threadIdx.x;
    const float4* g = (const float4*)(ws + ((size_t)b * 64 + l) * 8);
    float4 u0 = g[0], u1 = g[1];
    float v[8] = {u0.x, u0.y, u0.z, u0.w, u1.x, u1.y, u1.z, u1.w};

    float s256 = v[7] + __shfl_xor(v[7], 1); s256 += __shfl_xor(s256, 8);
    float e256 = ent(s256, 1.f / 65536.f);
    float E256 = e256 + __shfl_xor(e256, 2); E256 += __shfl_xor(E256, 4);
    E256 += __shfl_xor(E256, 16);  E256 += __shfl_xor(E256, 32);  // 16 distinct

    float sums[7];
#pragma unroll
    for (int j = 0; j < 7; ++j) sums[j] = bfly_sum(v[j]);

    if (l == 0) {
        const float invw[7] = {1.f / 262144.f, 1.f / 65536.f, 1.f / 16384.f,
                               1.f / 4096.f,   1.f / 1024.f,  1.f / 256.f, 1.f / 64.f};
        float* o = out + b * 8;
#pragma unroll
        for (int j = 0; j < 7; ++j) o[j] = sums[j] * invw[j];
        o[7] = E256 * (1.f / 16.f);
    }
}

extern "C" void kernel_launch(void* const* d_in, const int* in_sizes, int n_in,
                              void* d_out, int out_size, void* d_ws, size_t ws_size,
                              hipStream_t stream) {
    const float* x = (const float*)d_in[0];
    float* out = (float*)d_out;
    float* ws  = (float*)d_ws;  // 2048 blocks * 8 floats = 64 KiB

    slice_k1<<<32 * 64, 256, 0, stream>>>(x, ws);
    slice_k2<<<32, 64, 0, stream>>>(ws, out);
}

// Round 4
// 186.778 us; speedup vs baseline: 1.0190x; 1.0190x over previous
//
#include <hip/hip_runtime.h>

#define IMG 1024

// entropy of a window sum s with n = 1/inv_n elements: -(p0*log2 p0 + p1*log2 p1)
__device__ __forceinline__ float ent(float s, float inv_n) {
    float p1 = s * inv_n;
    float p0 = 1.0f - p1;
    float l1 = (p1 > 0.0f) ? __log2f(p1) : 0.0f;
    float l0 = (p0 > 0.0f) ? __log2f(p0) : 0.0f;
    return -(p0 * l0 + p1 * l1);
}

__device__ __forceinline__ float bfly_sum(float v) {
#pragma unroll
    for (int m = 32; m >= 1; m >>= 1) v += __shfl_xor(v, m);
    return v;  // full 64-lane sum, broadcast
}

// Kernel 1: block = 64x256 tile (2048 blocks). Wave = 16x256 band, thread =
// 16 rows x 4 cols strip. Every wave-load is one contiguous 1 KiB row segment.
// k=2/k=4 fully in-register (no shuffles, no duplication); k=8: shfl_xor(1)
// (dup x2); k=16: shfl_xor(2) (dup x4); k=32/64: 16-float LDS epilogue.
__global__ __launch_bounds__(256, 4) void slice_k1(const float* __restrict__ x,
                                                   float* __restrict__ ws) {
    const int b   = blockIdx.x >> 6;    // image
    const int tau = blockIdx.x & 63;    // 16x4 grid of 64x256 tiles
    const int ty = tau >> 2, tx = tau & 3;
    const int t = threadIdx.x;
    const int w = t >> 6, l = t & 63;

    const float* p = x + (size_t)b * (IMG * IMG)
                       + (size_t)(ty * 64 + w * 16) * IMG + (tx * 256 + l * 4);
    float4 v[16];
#pragma unroll
    for (int i = 0; i < 16; ++i)
        v[i] = *(const float4*)(p + (size_t)i * IMG);

    float e2 = 0.f, e4 = 0.f, e8 = 0.f;
    float s4h[8], s4[4];
#pragma unroll
    for (int i = 0; i < 8; ++i) {       // row pair (2i, 2i+1)
        float4 a = v[2 * i], c = v[2 * i + 1];
        float s2a = a.x + a.y + c.x + c.y;   // k=2 window, cols 4l..4l+1
        float s2b = a.z + a.w + c.z + c.w;   // k=2 window, cols 4l+2..4l+3
        e2 += ent(s2a, 0.25f) + ent(s2b, 0.25f);
        s4h[i] = s2a + s2b;                  // 2 rows x 4 cols
    }
#pragma unroll
    for (int j = 0; j < 4; ++j) {       // k=4: 4 rows x 4 cols, in-register
        s4[j] = s4h[2 * j] + s4h[2 * j + 1];
        e4 += ent(s4[j], 1.f / 16.f);
    }
    float s8[2];
#pragma unroll
    for (int m = 0; m < 2; ++m) {       // k=8: neighbor lane's 4 cols (dup x2)
        float t8 = s4[2 * m] + s4[2 * m + 1];
        s8[m] = t8 + __shfl_xor(t8, 1);
        e8 += ent(s8[m], 1.f / 64.f);
    }
    float t16 = s8[0] + s8[1];          // k=16 (dup x4)
    float s16 = t16 + __shfl_xor(t16, 2);
    float e16 = ent(s16, 1.f / 256.f);

    float E2 = bfly_sum(e2), E4 = bfly_sum(e4);
    float E8 = bfly_sum(e8), E16 = bfly_sum(e16);

    __shared__ float s16l[4][16];       // [wave][16-col group]
    __shared__ float wle[4][4];
    if ((l & 3) == 0) s16l[w][l >> 2] = s16;
    if (l == 0) { wle[w][0] = E2; wle[w][1] = E4; wle[w][2] = E8; wle[w][3] = E16; }
    __syncthreads();

    if (t < 16) {
        int r = t >> 3, c = t & 7;      // k=32: 2 wave-pairs x 8 col-groups
        float s32 = s16l[2 * r][2 * c] + s16l[2 * r][2 * c + 1]
                  + s16l[2 * r + 1][2 * c] + s16l[2 * r + 1][2 * c + 1];
        float e32 = ent(s32, 1.f / 1024.f);          // 16 distinct
        float a = s32 + __shfl_xor(s32, 1);
        float s64v = a + __shfl_xor(a, 8);           // s64[(t&7)>>1], dup x4
        float e64 = ent(s64v, 1.f / 4096.f);         // dup x4
#pragma unroll
        for (int m = 8; m >= 1; m >>= 1) {           // reduce over lanes 0..15
            e32 += __shfl_xor(e32, m);
            e64 += __shfl_xor(e64, m);
        }
        if (t < 8 && (t & 1) == 0)                   // 4 distinct s64 per block
            ws[b * 256 + ty * 16 + tx * 4 + (t >> 1)] = s64v;
        if (t == 0) {
            float* rec = ws + 8192 + (size_t)blockIdx.x * 8;
            rec[0] = wle[0][0] + wle[1][0] + wle[2][0] + wle[3][0];
            rec[1] = wle[0][1] + wle[1][1] + wle[2][1] + wle[3][1];
            rec[2] = (wle[0][2] + wle[1][2] + wle[2][2] + wle[3][2]) * 0.5f;
            rec[3] = (wle[0][3] + wle[1][3] + wle[2][3] + wle[3][3]) * 0.25f;
            rec[4] = e32;
            rec[5] = e64 * 0.25f;
            rec[6] = 0.f; rec[7] = 0.f;
        }
    }
}

// Kernel 2: per-image finish. Lane l sums block records; k=128/256 from the
// 16x16 s64 grid (lane l: row l>>2, cols 4*(l&3)..+3). Plain stores to out.
__global__ __launch_bounds__(64) void slice_k2(const float* __restrict__ ws,
                                               float* __restrict__ out) {
    const int b = blockIdx.x, l = threadIdx.x;
    const float* rec = ws + 8192 + ((size_t)b * 64 + l) * 8;
    float4 u0 = *(const float4*)rec;
    float u4 = rec[4], u5 = rec[5];
    float T0 = bfly_sum(u0.x), T1 = bfly_sum(u0.y);
    float T2 = bfly_sum(u0.z), T3 = bfly_sum(u0.w);
    float T4 = bfly_sum(u4),   T5 = bfly_sum(u5);

    float4 s = *(const float4*)(ws + (size_t)b * 256 + l * 4);
    float4 sv;                                   // merge s64 row pairs (dup x2)
    sv.x = s.x + __shfl_xor(s.x, 4);
    sv.y = s.y + __shfl_xor(s.y, 4);
    sv.z = s.z + __shfl_xor(s.z, 4);
    sv.w = s.w + __shfl_xor(s.w, 4);
    float a128 = sv.x + sv.y, b128 = sv.z + sv.w;  // two s128 per lane
    float e128 = ent(a128, 1.f / 16384.f) + ent(b128, 1.f / 16384.f);
    float h = a128 + b128;
    float s256 = h + __shfl_xor(h, 8);             // dup x4
    float e256 = ent(s256, 1.f / 65536.f);
    float T6 = bfly_sum(e128), T7 = bfly_sum(e256);

    if (l == 0) {
        float* o = out + b * 8;
        o[0] = T0 * (1.f / 262144.f);
        o[1] = T1 * (1.f / 65536.f);
        o[2] = T2 * (1.f / 16384.f);
        o[3] = T3 * (1.f / 4096.f);
        o[4] = T4 * (1.f / 1024.f);
        o[5] = T5 * (1.f / 256.f);
        o[6] = T6 * 0.5f * (1.f / 64.f);
        o[7] = T7 * 0.25f * (1.f / 16.f);
    }
}

extern "C" void kernel_launch(void* const* d_in, const int* in_sizes, int n_in,
                              void* d_out, int out_size, void* d_ws, size_t ws_size,
                              hipStream_t stream) {
    const float* x = (const float*)d_in[0];
    float* out = (float*)d_out;
    float* ws  = (float*)d_ws;  // 8192 s64 floats + 2048*8 record floats = 96 KiB

    slice_k1<<<32 * 64, 256, 0, stream>>>(x, ws);
    slice_k2<<<32, 64, 0, stream>>>(ws, out);
}

// Round 5
// 185.637 us; speedup vs baseline: 1.0252x; 1.0061x over previous
//
#include <hip/hip_runtime.h>

#define IMG 1024

// entropy of a window sum s with n = 1/inv_n elements: -(p0*log2 p0 + p1*log2 p1)
__device__ __forceinline__ float ent(float s, float inv_n) {
    float p1 = s * inv_n;
    float p0 = 1.0f - p1;
    float l1 = (p1 > 0.0f) ? __log2f(p1) : 0.0f;
    float l0 = (p0 > 0.0f) ? __log2f(p0) : 0.0f;
    return -(p0 * l0 + p1 * l1);
}

__device__ __forceinline__ float bfly_sum(float v) {
#pragma unroll
    for (int m = 32; m >= 1; m >>= 1) v += __shfl_xor(v, m);
    return v;  // full 64-lane sum, broadcast
}

// Kernel 1: block = 32x256 tile (4096 blocks). Wave = 8x256 band, thread =
// 8 rows x 4 cols (8 live float4 = 32 VGPRs -> fits 64-VGPR cap for 8 waves/EU).
// Every wave-load is one contiguous 1 KiB row segment.
// k=2/k=4 in-register; k=8: shfl_xor(1); k=16/k=32: wave-0 LDS epilogue.
// ws layout: [0, 32*1024) per-image 32x32 s32 grids; [32768, +4096*8) block records.
__global__ __launch_bounds__(256, 8) void slice_k1(const float* __restrict__ x,
                                                   float* __restrict__ ws) {
    const int b    = blockIdx.x >> 7;    // image
    const int tile = blockIdx.x & 127;   // 32 row-bands x 4 col-blocks
    const int R = tile >> 2, C = tile & 3;
    const int t = threadIdx.x;
    const int w = t >> 6, l = t & 63;

    const float* p = x + (size_t)b * (IMG * IMG)
                       + (size_t)(R * 32 + w * 8) * IMG + (C * 256 + l * 4);
    float4 v[8];
#pragma unroll
    for (int i = 0; i < 8; ++i)
        v[i] = *(const float4*)(p + (size_t)i * IMG);

    float e2 = 0.f, e4 = 0.f;
    float s4h[4];
#pragma unroll
    for (int i = 0; i < 4; ++i) {        // row pair (2i, 2i+1)
        float4 a = v[2 * i], c = v[2 * i + 1];
        float s2a = a.x + a.y + c.x + c.y;
        float s2b = a.z + a.w + c.z + c.w;
        e2 += ent(s2a, 0.25f) + ent(s2b, 0.25f);
        s4h[i] = s2a + s2b;              // 2 rows x 4 cols
    }
    float s4a = s4h[0] + s4h[1], s4b = s4h[2] + s4h[3];   // k=4, in-register
    e4 = ent(s4a, 1.f / 16.f) + ent(s4b, 1.f / 16.f);
    float t8 = s4a + s4b;                // k=8: 8 rows, neighbor lane's 4 cols
    float s8 = t8 + __shfl_xor(t8, 1);   // dup x2
    float e8 = ent(s8, 1.f / 64.f);

    float E2 = bfly_sum(e2), E4 = bfly_sum(e4), E8 = bfly_sum(e8);

    __shared__ float s8l[4][32];         // [wave][8-col group]
    __shared__ float wle[4][3];
    if ((l & 1) == 0) s8l[w][l >> 1] = s8;
    if (l == 0) { wle[w][0] = E2; wle[w][1] = E4; wle[w][2] = E8 * 0.5f; }
    __syncthreads();

    if (w == 0) {                        // block-level k=16 / k=32, one wave
        int r = (l >> 4) & 1, c = l & 15;  // lanes 32-63 duplicate (dup x2)
        float s16 = s8l[2 * r][2 * c]     + s8l[2 * r][2 * c + 1]
                  + s8l[2 * r + 1][2 * c] + s8l[2 * r + 1][2 * c + 1];
        float e16 = ent(s16, 1.f / 256.f);
        float u = s16 + __shfl_xor(s16, 1);
        float s32 = u + __shfl_xor(u, 16);            // dup x8
        float e32 = ent(s32, 1.f / 1024.f);
        float E16 = bfly_sum(e16) * 0.5f;             // 32 distinct
        float E32 = bfly_sum(e32) * 0.125f;           // 8 distinct
        if (l < 16 && (l & 1) == 0)                   // distinct s32: j = l>>1
            ws[(size_t)b * 1024 + R * 32 + C * 8 + (l >> 1)] = s32;
        if (l == 0) {
            float* rec = ws + 32768 + (size_t)blockIdx.x * 8;
            rec[0] = wle[0][0] + wle[1][0] + wle[2][0] + wle[3][0];
            rec[1] = wle[0][1] + wle[1][1] + wle[2][1] + wle[3][1];
            rec[2] = wle[0][2] + wle[1][2] + wle[2][2] + wle[3][2];
            rec[3] = E16;
            rec[4] = E32;
        }
    }
}

// Kernel 2: per-image finish (32 blocks x 256 threads). Sums 128 block
// records, then pyramids the 32x32 s32 grid -> k=64/128/256. Plain stores.
__global__ __launch_bounds__(256) void slice_k2(const float* __restrict__ ws,
                                                float* __restrict__ out) {
    const int b = blockIdx.x, t = threadIdx.x;
    const int w = t >> 6, l = t & 63;

    __shared__ float g[1024];            // s32 grid
    ((float4*)g)[t] = ((const float4*)(ws + (size_t)b * 1024))[t];

    float r0 = 0.f, r1 = 0.f, r2 = 0.f, r3 = 0.f, r4 = 0.f;
    if (t < 128) {
        const float* rec = ws + 32768 + ((size_t)(b * 128 + t)) * 8;
        float4 a = *(const float4*)rec;
        r0 = a.x; r1 = a.y; r2 = a.z; r3 = a.w; r4 = rec[4];
    }
    r0 = bfly_sum(r0); r1 = bfly_sum(r1); r2 = bfly_sum(r2);
    r3 = bfly_sum(r3); r4 = bfly_sum(r4);
    __shared__ float wr[4][5];
    __shared__ float w64s[4];
    __shared__ float l64[256];
    if (l == 0) { wr[w][0] = r0; wr[w][1] = r1; wr[w][2] = r2; wr[w][3] = r3; wr[w][4] = r4; }
    __syncthreads();

    // k=64: 16x16 windows, one per thread
    int i = t >> 4, j = t & 15;
    float s64 = g[(2 * i) * 32 + 2 * j]     + g[(2 * i) * 32 + 2 * j + 1]
              + g[(2 * i + 1) * 32 + 2 * j] + g[(2 * i + 1) * 32 + 2 * j + 1];
    float e64 = ent(s64, 1.f / 4096.f);
    l64[t] = s64;
    float E64w = bfly_sum(e64);
    if (l == 0) w64s[w] = E64w;
    __syncthreads();

    if (w == 0) {                        // k=128 (64 windows = 64 lanes), k=256
        int i2 = l >> 3, j2 = l & 7;
        float s128 = l64[(2 * i2) * 16 + 2 * j2]     + l64[(2 * i2) * 16 + 2 * j2 + 1]
                   + l64[(2 * i2 + 1) * 16 + 2 * j2] + l64[(2 * i2 + 1) * 16 + 2 * j2 + 1];
        float e128 = ent(s128, 1.f / 16384.f);
        float E128 = bfly_sum(e128);
        float u = s128 + __shfl_xor(s128, 1);
        float s256 = u + __shfl_xor(u, 8);           // dup x4
        float e256 = ent(s256, 1.f / 65536.f);
        float E256 = bfly_sum(e256) * 0.25f;         // 16 distinct
        if (l == 0) {
            float E2 = wr[0][0] + wr[1][0] + wr[2][0] + wr[3][0];
            float E4 = wr[0][1] + wr[1][1] + wr[2][1] + wr[3][1];
            float E8 = wr[0][2] + wr[1][2] + wr[2][2] + wr[3][2];
            float E16 = wr[0][3] + wr[1][3] + wr[2][3] + wr[3][3];
            float E32 = wr[0][4] + wr[1][4] + wr[2][4] + wr[3][4];
            float E64 = w64s[0] + w64s[1] + w64s[2] + w64s[3];
            float* o = out + b * 8;
            o[0] = E2  * (1.f / 262144.f);
            o[1] = E4  * (1.f / 65536.f);
            o[2] = E8  * (1.f / 16384.f);
            o[3] = E16 * (1.f / 4096.f);
            o[4] = E32 * (1.f / 1024.f);
            o[5] = E64 * (1.f / 256.f);
            o[6] = E128 * (1.f / 64.f);
            o[7] = E256 * (1.f / 16.f);
        }
    }
}

extern "C" void kernel_launch(void* const* d_in, const int* in_sizes, int n_in,
                              void* d_out, int out_size, void* d_ws, size_t ws_size,
                              hipStream_t stream) {
    const float* x = (const float*)d_in[0];
    float* out = (float*)d_out;
    float* ws  = (float*)d_ws;  // 128 KiB grids + 128 KiB records

    slice_k1<<<32 * 128, 256, 0, stream>>>(x, ws);
    slice_k2<<<32, 256, 0, stream>>>(ws, out);
}